// Round 1
// baseline (99.922 us; speedup 1.0000x reference)
//
#include <hip/hip_runtime.h>

// FractalEmbedding: cs[M,2] -> 8 Julia iterations -> feats[M,16]
//                   out[M,D] = feats @ W^T * scale   (W is [D,16] row-major)
// M = B*L = 32768, D = 2048, output fp32 = 256 MiB -> write-BW-bound (~42us floor).

#define STEPS 8
#define KF 16                 // 2*STEPS feature columns
#define DDIM 2048
#define BLOCK 256
#define DPT 4                 // d-values per thread (one float4 store)
#define D_PER_BLK (BLOCK * DPT)       // 1024
#define D_BLOCKS (DDIM / D_PER_BLK)   // 2
#define ROWS_PER_BLK 32

static_assert(D_BLOCKS == 2, "rblk shift assumes 2 d-blocks");

__global__ __launch_bounds__(BLOCK) void fractal_embed_kernel(
    const float* __restrict__ cs,     // [M,2] interleaved (cr, ci)
    const float* __restrict__ W,      // [D,16] row-major
    const float* __restrict__ scale,  // [1]
    float* __restrict__ out)          // [M,D]
{
    const int tid  = threadIdx.x;
    const int dblk = blockIdx.x & (D_BLOCKS - 1);
    const int rblk = blockIdx.x >> 1;
    const int d0   = dblk * D_PER_BLK + tid * DPT;

    // W rows d0..d0+3 into registers (64 floats). W is 128 KB total -> L2-hot.
    float4 w[DPT][4];
#pragma unroll
    for (int r = 0; r < DPT; ++r) {
        const float4* wp = reinterpret_cast<const float4*>(W + (size_t)(d0 + r) * KF);
#pragma unroll
        for (int q = 0; q < 4; ++q) w[r][q] = wp[q];
    }
    const float s = scale[0];

    const int row0 = rblk * ROWS_PER_BLK;
#pragma unroll 1
    for (int rr = 0; rr < ROWS_PER_BLK; ++rr) {
        const int row = row0 + rr;
        const float2 c = reinterpret_cast<const float2*>(cs)[row];  // wave-broadcast

        // Julia iteration z <- z^2 + c from z=0, record (zr, zi) each step.
        float f[KF];
        float zr = 0.0f, zi = 0.0f;
#pragma unroll
        for (int st = 0; st < STEPS; ++st) {
            const float nzr = fmaf(zr, zr, fmaf(-zi, zi, c.x));
            const float nzi = fmaf(2.0f * zr, zi, c.y);
            zr = nzr; zi = nzi;
            f[2 * st]     = zr;
            f[2 * st + 1] = zi;
        }

        // 4 dot products of length 16 against register-resident W rows.
        float acc[DPT];
#pragma unroll
        for (int r = 0; r < DPT; ++r) {
            float a = 0.0f;
#pragma unroll
            for (int q = 0; q < 4; ++q) {
                a = fmaf(f[4 * q + 0], w[r][q].x, a);
                a = fmaf(f[4 * q + 1], w[r][q].y, a);
                a = fmaf(f[4 * q + 2], w[r][q].z, a);
                a = fmaf(f[4 * q + 3], w[r][q].w, a);
            }
            acc[r] = a * s;
        }

        float4 o = make_float4(acc[0], acc[1], acc[2], acc[3]);
        reinterpret_cast<float4*>(out + (size_t)row * DDIM)[d0 >> 2] = o;
    }
}

extern "C" void kernel_launch(void* const* d_in, const int* in_sizes, int n_in,
                              void* d_out, int out_size, void* d_ws, size_t ws_size,
                              hipStream_t stream) {
    // d_in[0] = token_ids (int64, unused — cs is precomputed host-side)
    // d_in[1] = cs    [B,L,2] float32
    // d_in[2] = W     [D,16]  float32
    // d_in[3] = scale [1]     float32
    const float* cs    = (const float*)d_in[1];
    const float* W     = (const float*)d_in[2];
    const float* scale = (const float*)d_in[3];
    float* out         = (float*)d_out;

    const int M = in_sizes[0];                 // B*L = 32768 rows
    const int grid = D_BLOCKS * (M / ROWS_PER_BLK);  // 2 * 1024 = 2048 blocks
    fractal_embed_kernel<<<grid, BLOCK, 0, stream>>>(cs, W, scale, out);
}

// Round 2
// 60.295 us; speedup vs baseline: 1.6572x; 1.6572x over previous
//
#include <hip/hip_runtime.h>

// FractalEmbedding: cs[M,2] -> 8 Julia iterations -> feats[M,16]
//                   out[M,D] = feats @ W^T * scale   (W is [D,16] row-major)
// M = 32768, D = 2048, fp32 out = 256 MiB -> write-BW-bound (~38us @ 7 TB/s).
//
// R2: cs staged in LDS (kills per-row global-load latency), unroll-2 row loop
//     (cross-row pipelining), nontemporal float4 stores (don't thrash L2).

#define STEPS 8
#define KF 16                 // 2*STEPS feature columns
#define DDIM 2048
#define BLOCK 256
#define DPT 4                 // d-values per thread (one float4 store)
#define D_PER_BLK (BLOCK * DPT)       // 1024
#define D_BLOCKS (DDIM / D_PER_BLK)   // 2
#define ROWS_PER_BLK 32

static_assert(D_BLOCKS == 2, "rblk shift assumes 2 d-blocks");

typedef float f32x4 __attribute__((ext_vector_type(4)));

__global__ __launch_bounds__(BLOCK) void fractal_embed_kernel(
    const float* __restrict__ cs,     // [M,2] interleaved (cr, ci)
    const float* __restrict__ W,      // [D,16] row-major
    const float* __restrict__ scale,  // [1]
    float* __restrict__ out)          // [M,D]
{
    const int tid  = threadIdx.x;
    const int dblk = blockIdx.x & (D_BLOCKS - 1);
    const int rblk = blockIdx.x >> 1;
    const int d0   = dblk * D_PER_BLK + tid * DPT;
    const int row0 = rblk * ROWS_PER_BLK;

    // Stage this block's 32 (cr,ci) pairs into LDS: one coalesced 256 B load.
    __shared__ float s_cs[2 * ROWS_PER_BLK];
    if (tid < 2 * ROWS_PER_BLK)
        s_cs[tid] = cs[(size_t)row0 * 2 + tid];

    // W rows d0..d0+3 into registers (64 VGPRs). W = 128 KB total -> L2-hot.
    f32x4 w[DPT][KF / 4];
#pragma unroll
    for (int r = 0; r < DPT; ++r) {
        const f32x4* wp = reinterpret_cast<const f32x4*>(W + (size_t)(d0 + r) * KF);
#pragma unroll
        for (int q = 0; q < KF / 4; ++q) w[r][q] = wp[q];
    }
    const float s = scale[0];

    __syncthreads();

#pragma unroll 2
    for (int rr = 0; rr < ROWS_PER_BLK; ++rr) {
        const int row = row0 + rr;
        const float cr = s_cs[2 * rr];       // ds_read broadcast, conflict-free
        const float ci = s_cs[2 * rr + 1];

        // Julia iteration z <- z^2 + c from z=0, record (zr, zi) each step.
        float f[KF];
        float zr = 0.0f, zi = 0.0f;
#pragma unroll
        for (int st = 0; st < STEPS; ++st) {
            const float nzr = fmaf(zr, zr, fmaf(-zi, zi, cr));
            const float nzi = fmaf(2.0f * zr, zi, ci);
            zr = nzr; zi = nzi;
            f[2 * st]     = zr;
            f[2 * st + 1] = zi;
        }

        // 4 dot products of length 16 against register-resident W rows.
        f32x4 o;
#pragma unroll
        for (int r = 0; r < DPT; ++r) {
            float a = 0.0f;
#pragma unroll
            for (int q = 0; q < KF / 4; ++q) {
                a = fmaf(f[4 * q + 0], w[r][q].x, a);
                a = fmaf(f[4 * q + 1], w[r][q].y, a);
                a = fmaf(f[4 * q + 2], w[r][q].z, a);
                a = fmaf(f[4 * q + 3], w[r][q].w, a);
            }
            o[r] = a * s;
        }

        f32x4* op = reinterpret_cast<f32x4*>(out + (size_t)row * DDIM + d0);
        __builtin_nontemporal_store(o, op);   // streaming write, skip L2 reuse
    }
}

extern "C" void kernel_launch(void* const* d_in, const int* in_sizes, int n_in,
                              void* d_out, int out_size, void* d_ws, size_t ws_size,
                              hipStream_t stream) {
    // d_in[0] = token_ids (int64, unused — cs is precomputed host-side)
    // d_in[1] = cs    [B,L,2] float32
    // d_in[2] = W     [D,16]  float32
    // d_in[3] = scale [1]     float32
    const float* cs    = (const float*)d_in[1];
    const float* W     = (const float*)d_in[2];
    const float* scale = (const float*)d_in[3];
    float* out         = (float*)d_out;

    const int M = in_sizes[0];                       // B*L = 32768 rows
    const int grid = D_BLOCKS * (M / ROWS_PER_BLK);  // 2 * 1024 = 2048 blocks
    fractal_embed_kernel<<<grid, BLOCK, 0, stream>>>(cs, W, scale, out);
}

// Round 3
// 58.763 us; speedup vs baseline: 1.7004x; 1.0261x over previous
//
#include <hip/hip_runtime.h>

// FractalEmbedding: cs[M,2] -> 8 Julia iterations -> feats[M,16]
//                   out[M,D] = feats @ W^T * scale   (W is [D,16] row-major)
// M = 32768, D = 2048, fp32 out = 256 MiB  (== L3 size -> let L3 absorb it).
//
// R3: drop nontemporal stores (256 MiB stream fits Infinity Cache; nt forced
//     every byte to HBM), pack dot product as f32x2 -> v_pk_fma_f32 (halves
//     VALU issue), keep LDS-staged cs + unroll-2 row pipelining.

#define STEPS 8
#define KF 16                 // 2*STEPS feature columns
#define DDIM 2048
#define BLOCK 256
#define DPT 4                 // d-values per thread (one float4 store)
#define D_PER_BLK (BLOCK * DPT)       // 1024
#define D_BLOCKS (DDIM / D_PER_BLK)   // 2
#define ROWS_PER_BLK 32

static_assert(D_BLOCKS == 2, "rblk shift assumes 2 d-blocks");

typedef float f32x2 __attribute__((ext_vector_type(2)));
typedef float f32x4 __attribute__((ext_vector_type(4)));

__global__ __launch_bounds__(BLOCK) void fractal_embed_kernel(
    const float* __restrict__ cs,     // [M,2] interleaved (cr, ci)
    const float* __restrict__ W,      // [D,16] row-major
    const float* __restrict__ scale,  // [1]
    float* __restrict__ out)          // [M,D]
{
    const int tid  = threadIdx.x;
    const int dblk = blockIdx.x & (D_BLOCKS - 1);
    const int rblk = blockIdx.x >> 1;
    const int d0   = dblk * D_PER_BLK + tid * DPT;
    const int row0 = rblk * ROWS_PER_BLK;

    // Stage this block's 32 (cr,ci) pairs into LDS: one coalesced 256 B load.
    __shared__ float s_cs[2 * ROWS_PER_BLK];
    if (tid < 2 * ROWS_PER_BLK)
        s_cs[tid] = cs[(size_t)row0 * 2 + tid];

    // W rows d0..d0+3 into registers as f32x2 pairs (64 VGPRs total).
    f32x2 w2[DPT][KF / 2];
#pragma unroll
    for (int r = 0; r < DPT; ++r) {
        const f32x2* wp = reinterpret_cast<const f32x2*>(W + (size_t)(d0 + r) * KF);
#pragma unroll
        for (int q = 0; q < KF / 2; ++q) w2[r][q] = wp[q];
    }
    const float s = scale[0];

    __syncthreads();

#pragma unroll 2
    for (int rr = 0; rr < ROWS_PER_BLK; ++rr) {
        const int row = row0 + rr;
        const float cr = s_cs[2 * rr];       // ds_read broadcast, conflict-free
        const float ci = s_cs[2 * rr + 1];

        // Julia iteration z <- z^2 + c from z=0; f2[st] = (zr, zi).
        f32x2 f2[STEPS];
        float zr = 0.0f, zi = 0.0f;
#pragma unroll
        for (int st = 0; st < STEPS; ++st) {
            const float nzr = fmaf(zr, zr, fmaf(-zi, zi, cr));
            const float nzi = fmaf(zr + zr, zi, ci);
            zr = nzr; zi = nzi;
            f2[st].x = zr;
            f2[st].y = zi;
        }

        // 4 dot products of length 16, packed: 8 v_pk_fma_f32 each.
        f32x4 o;
#pragma unroll
        for (int r = 0; r < DPT; ++r) {
            f32x2 a2 = {0.0f, 0.0f};
#pragma unroll
            for (int q = 0; q < KF / 2; ++q)
                a2 = __builtin_elementwise_fma(f2[q], w2[r][q], a2);
            o[r] = (a2.x + a2.y) * s;
        }

        reinterpret_cast<f32x4*>(out + (size_t)row * DDIM + d0)[0] = o;
    }
}

extern "C" void kernel_launch(void* const* d_in, const int* in_sizes, int n_in,
                              void* d_out, int out_size, void* d_ws, size_t ws_size,
                              hipStream_t stream) {
    // d_in[0] = token_ids (int64, unused — cs is precomputed host-side)
    // d_in[1] = cs    [B,L,2] float32
    // d_in[2] = W     [D,16]  float32
    // d_in[3] = scale [1]     float32
    const float* cs    = (const float*)d_in[1];
    const float* W     = (const float*)d_in[2];
    const float* scale = (const float*)d_in[3];
    float* out         = (float*)d_out;

    const int M = in_sizes[0];                       // B*L = 32768 rows
    const int grid = D_BLOCKS * (M / ROWS_PER_BLK);  // 2 * 1024 = 2048 blocks
    fractal_embed_kernel<<<grid, BLOCK, 0, stream>>>(cs, W, scale, out);
}